// Round 1
// baseline (3665.329 us; speedup 1.0000x reference)
//
#include <hip/hip_runtime.h>

#define BATCH 16
#define CH 512
#define OC 1536
#define KDIM 1024
#define LMAX 4096
#define WT_ELEMS (KDIM * OC)

#define TL 64   // output columns per block
#define CM 64   // rows per gate part
#define ROWS 192
#define KC 32   // K chunk

__device__ __forceinline__ int nfp2_of(int n) { return 1 << (31 - __clz(n)); }

// ---------------- W transpose: W[o][k] -> Wt[k][o] ----------------
__global__ __launch_bounds__(256) void transpose_W_k(const float* __restrict__ W,
                                                     float* __restrict__ Wt) {
  __shared__ float t[32][33];
  int o0 = blockIdx.x * 32, k0 = blockIdx.y * 32;
  int lx = threadIdx.x & 31, ly = threadIdx.x >> 5;
#pragma unroll
  for (int i = 0; i < 32; i += 8)
    t[ly + i][lx] = W[(size_t)(o0 + ly + i) * KDIM + k0 + lx];
  __syncthreads();
#pragma unroll
  for (int i = 0; i < 32; i += 8)
    Wt[(size_t)(k0 + ly + i) * OC + o0 + lx] = t[lx][ly + i];
}

// ---------------- suffix copy: cur0[b,c,half+e] = h[b,c,2*half+e] ----------------
__global__ __launch_bounds__(256) void copy_suffix_k(const float* __restrict__ h,
                                                     const int* __restrict__ Nvec,
                                                     float* __restrict__ ws,
                                                     float* __restrict__ dout) {
  int b = blockIdx.z;
  int c = blockIdx.y;
  int n = Nvec[b];
  int nfp2 = nfp2_of(n);
  int half = n - nfp2;
  int cnt = nfp2 - half;
  long off = 0;
  for (int i = 0; i < BATCH; ++i)
    if (i < b) off += nfp2_of(Nvec[i]);
  float* dst = ws + WT_ELEMS + off * CH + (size_t)c * nfp2;
  const float* src = h + (size_t)b * CH * LMAX + (size_t)c * LMAX + 2 * half;
  int e0 = blockIdx.x * 1024 + threadIdx.x;
#pragma unroll
  for (int u = 0; u < 4; ++u) {
    int e = e0 + u * 256;
    if (e < cnt) {
      float v = src[e];
      dst[half + e] = v;
      if (nfp2 == 1) dout[(size_t)b * CH + c] = v;  // degenerate N==1 case
    }
  }
}

// ---------------- one reduction level: gated GEMM ----------------
// level 0: input = h, cols = N - Nfp2 (prologue reduce part)
// level l>=1: input = previous level buffer, cols = (Nfp2 >> (l-1)) / 2
__global__ __launch_bounds__(256) void level_gemm_k(const float* __restrict__ h,
                                                    const float* __restrict__ bias,
                                                    const int* __restrict__ Nvec,
                                                    float* __restrict__ ws,
                                                    float* __restrict__ dout, int level) {
  __shared__ float Wsm[KC][ROWS];
  __shared__ float Xsm[KC][TL];

  const int b = blockIdx.z;
  const int tid = threadIdx.x;
  const int n = Nvec[b];
  const int nfp2 = nfp2_of(n);

  long totA = 0, off_in = 0, off_out = 0;
  const int sh_in = (level > 0) ? (level - 1) : 0;
  for (int i = 0; i < BATCH; ++i) {
    int f = nfp2_of(Nvec[i]);
    totA += f;
    if (i < b) { off_in += f >> sh_in; off_out += f >> level; }
  }
  float* bufA = ws + WT_ELEMS;
  float* bufB = bufA + totA * CH;

  int cols, stride_in, stride_out;
  const float* inp;
  float* outp;
  stride_out = nfp2 >> level;
  if (level == 0) {
    cols = n - nfp2;
    stride_in = LMAX;
    inp = h + (size_t)b * CH * LMAX;
    outp = bufA + off_out * CH;
  } else {
    int w_in = nfp2 >> (level - 1);
    if (w_in < 2) return;  // batch finished earlier
    cols = w_in >> 1;
    stride_in = w_in;
    inp = ((level & 1) ? bufA : bufB) + off_in * CH;
    outp = ((level & 1) ? bufB : bufA) + off_out * CH;
  }
  const int l0 = blockIdx.x * TL;
  if (l0 >= cols) return;
  const int o0 = blockIdx.y * CM;
  const float* Wt = ws;

  const int tx = tid & 15;   // column group
  const int ty = tid >> 4;   // row group

  float acc[3][4][4];
#pragma unroll
  for (int p = 0; p < 3; ++p)
#pragma unroll
    for (int i = 0; i < 4; ++i)
#pragma unroll
      for (int j = 0; j < 4; ++j) acc[p][i][j] = 0.0f;

  // precompute staging addresses
  const float* xp[4];
  float *xd0[4], *xd1[4];
  bool xok[4];
#pragma unroll
  for (int q = 0; q < 4; ++q) {
    int id = q * 256 + tid;
    int cl = id >> 6;       // 0..15 (c within chunk)
    int lx = id & 63;       // column within tile
    int lcol = l0 + lx;
    xok[q] = (lcol < cols);
    xp[q] = inp + (size_t)cl * stride_in + 2 * lcol;
    xd0[q] = &Xsm[2 * cl][lx];
    xd1[q] = &Xsm[2 * cl + 1][lx];
  }
  const float* wp[6];
  float* wd[6];
#pragma unroll
  for (int q = 0; q < 6; ++q) {
    int id = q * 256 + tid;
    int kk = id / 48;
    int rem = id - kk * 48;
    int p = rem >> 4;
    int qq = rem & 15;
    wp[q] = Wt + (size_t)kk * OC + p * CH + o0 + qq * 4;
    wd[q] = &Wsm[kk][p * CM + qq * 4];
  }

  for (int kc = 0; kc < KDIM; kc += KC) {
#pragma unroll
    for (int q = 0; q < 4; ++q) {
      float2 v;
      v.x = 0.0f; v.y = 0.0f;
      if (xok[q]) v = *(const float2*)xp[q];
      xp[q] += 16 * stride_in;
      *xd0[q] = v.x;
      *xd1[q] = v.y;
    }
#pragma unroll
    for (int q = 0; q < 6; ++q) {
      float4 w = *(const float4*)wp[q];
      wp[q] += KC * OC;
      *(float4*)wd[q] = w;
    }
    __syncthreads();
#pragma unroll 8
    for (int kk = 0; kk < KC; ++kk) {
      float4 xv = *(const float4*)&Xsm[kk][tx * 4];
      float xr[4] = {xv.x, xv.y, xv.z, xv.w};
      float4 w0 = *(const float4*)&Wsm[kk][0 * CM + ty * 4];
      float4 w1 = *(const float4*)&Wsm[kk][1 * CM + ty * 4];
      float4 w2 = *(const float4*)&Wsm[kk][2 * CM + ty * 4];
      float wr[3][4] = {{w0.x, w0.y, w0.z, w0.w},
                        {w1.x, w1.y, w1.z, w1.w},
                        {w2.x, w2.y, w2.z, w2.w}};
#pragma unroll
      for (int p = 0; p < 3; ++p)
#pragma unroll
        for (int i = 0; i < 4; ++i)
#pragma unroll
          for (int j = 0; j < 4; ++j)
            acc[p][i][j] = fmaf(wr[p][i], xr[j], acc[p][i][j]);
    }
    __syncthreads();
  }

  // epilogue: gate and store
#pragma unroll
  for (int i = 0; i < 4; ++i) {
    int r = o0 + ty * 4 + i;
    float bl = bias[r];
    float br = bias[CH + r];
    float bg = bias[2 * CH + r];
#pragma unroll
    for (int j = 0; j < 4; ++j) {
      int lcol = l0 + tx * 4 + j;
      if (lcol >= cols) continue;
      float zl = acc[0][i][j] + bl;
      float zr = acc[1][i][j] + br;
      float zg = acc[2][i][j] + bg;
      float g = 1.0f / (1.0f + __expf(-zg));
      float rt = 1.0f - 2.0f / (1.0f + __expf(2.0f * zr));
      float val = zl * g + rt * (1.0f - g);
      if (stride_out == 1)
        dout[(size_t)b * CH + r] = val;  // final level for this batch
      else
        outp[(size_t)r * stride_out + lcol] = val;
    }
  }
}

extern "C" void kernel_launch(void* const* d_in, const int* in_sizes, int n_in,
                              void* d_out, int out_size, void* d_ws, size_t ws_size,
                              hipStream_t stream) {
  const float* h = (const float*)d_in[0];
  const float* W = (const float*)d_in[1];
  const float* bias = (const float*)d_in[2];
  const int* Nvec = (const int*)d_in[3];
  float* dout = (float*)d_out;
  float* wsf = (float*)d_ws;

  // 1) transpose W into ws[0 .. WT_ELEMS)
  transpose_W_k<<<dim3(OC / 32, KDIM / 32), 256, 0, stream>>>(W, wsf);
  // 2) suffix copy into level-0 buffer
  copy_suffix_k<<<dim3(4, CH, BATCH), 256, 0, stream>>>(h, Nvec, wsf, dout);
  // 3) prologue reduce (level 0): worst-case cols = 2047 -> 32 tiles
  level_gemm_k<<<dim3(32, 8, BATCH), 256, 0, stream>>>(h, bias, Nvec, wsf, dout, 0);
  // 4) tree levels
  for (int lev = 1; lev <= 12; ++lev) {
    int colsmax = LMAX >> lev;
    int tiles = (colsmax + TL - 1) / TL;
    level_gemm_k<<<dim3(tiles, 8, BATCH), 256, 0, stream>>>(h, bias, Nvec, wsf, dout, lev);
  }
}

// Round 2
// 1736.223 us; speedup vs baseline: 2.1111x; 2.1111x over previous
//
#include <hip/hip_runtime.h>

#define BATCH 16
#define CH 512
#define OC 1536
#define KDIM 1024
#define LMAX 4096
#define WGLOB_SZ 6291456  // 32 kc * 1536 rows * 128 B

typedef __attribute__((ext_vector_type(8))) short s8v;
typedef __attribute__((ext_vector_type(4))) float f4v;

__device__ __forceinline__ int nfp2_of(int n) { return 1 << (31 - __clz(n)); }

__device__ __forceinline__ unsigned short f2bf(float x) {
  union { float f; unsigned u; } v; v.f = x;
  unsigned r = v.u + 0x7fffu + ((v.u >> 16) & 1u);
  return (unsigned short)(r >> 16);
}
__device__ __forceinline__ float bf2f(unsigned short b) {
  union { unsigned u; float f; } v; v.u = ((unsigned)b) << 16; return v.f;
}
__device__ __forceinline__ void hilo(float x, unsigned short& hi, unsigned short& lo) {
  hi = f2bf(x);
  lo = f2bf(x - bf2f(hi));
}

// per-batch arena layout (all device-computed from Nvec)
__device__ __forceinline__ void layout(const int* __restrict__ Nvec, int b,
                                       size_t& offC0, size_t& offA, size_t& offB,
                                       int& n, int& nfp2, int& half) {
  size_t c0t = 0, at = 0, bt = 0, c0o = 0, ao = 0, bo = 0;
  n = 2; nfp2 = 2; half = 0;
#pragma unroll 1
  for (int i = 0; i < BATCH; ++i) {
    int ni = Nvec[i];
    int f = nfp2_of(ni);
    int hf = ni - f;
    size_t cs = (size_t)((hf + 127) & ~127) << 12;  // rounded cols * 4096 B
    size_t as = (size_t)(f >> 1) << 12;
    size_t bs = (size_t)(f >> 2) << 12;
    if (i < b) { c0o += cs; ao += as; bo += bs; }
    if (i == b) { n = ni; nfp2 = f; half = hf; }
    c0t += cs; at += as; bt += bs;
  }
  offC0 = (size_t)WGLOB_SZ + c0o;
  offA = (size_t)WGLOB_SZ + c0t + ao;
  offB = (size_t)WGLOB_SZ + c0t + at + bo;
}

__device__ __forceinline__ void gload16(const void* g, void* l) {
  __builtin_amdgcn_global_load_lds((const __attribute__((address_space(1))) void*)g,
                                   (__attribute__((address_space(3))) void*)l, 16, 0, 0);
}

// ---------- W prep: W[o][k] fp32 -> Wglob[kc][o][hi 32bf16 | lo 32bf16] ----------
__global__ __launch_bounds__(256) void prep_w_k(const float* __restrict__ W, char* __restrict__ ws) {
  int idx = blockIdx.x * 256 + threadIdx.x;  // idx = kc*1536 + o
  if (idx >= 32 * 1536) return;
  int kc = idx / 1536;
  int o = idx - kc * 1536;
  const float* src = W + (size_t)o * KDIM + kc * 32;
  unsigned short hb[32], lb[32];
#pragma unroll
  for (int t = 0; t < 32; ++t) hilo(src[t], hb[t], lb[t]);
  char* dst = ws + ((size_t)idx << 7);
  uint4* d4 = (uint4*)dst;
#pragma unroll
  for (int q = 0; q < 4; ++q) {
    uint4 v;
    v.x = (unsigned)hb[q*8+0] | ((unsigned)hb[q*8+1] << 16);
    v.y = (unsigned)hb[q*8+2] | ((unsigned)hb[q*8+3] << 16);
    v.z = (unsigned)hb[q*8+4] | ((unsigned)hb[q*8+5] << 16);
    v.w = (unsigned)hb[q*8+6] | ((unsigned)hb[q*8+7] << 16);
    d4[q] = v;
  }
#pragma unroll
  for (int q = 0; q < 4; ++q) {
    uint4 v;
    v.x = (unsigned)lb[q*8+0] | ((unsigned)lb[q*8+1] << 16);
    v.y = (unsigned)lb[q*8+2] | ((unsigned)lb[q*8+3] << 16);
    v.z = (unsigned)lb[q*8+4] | ((unsigned)lb[q*8+5] << 16);
    v.w = (unsigned)lb[q*8+6] | ((unsigned)lb[q*8+7] << 16);
    d4[4 + q] = v;
  }
}

// ---------- level-0 input conversion: h pairs -> conv0[l][hl][k] bf16 ----------
__global__ __launch_bounds__(256) void conv0_k(const float* __restrict__ h,
                                               const int* __restrict__ Nvec,
                                               char* __restrict__ ws) {
  int b = blockIdx.z;
  size_t offC0, offA, offB; int n, nfp2, half;
  layout(Nvec, b, offC0, offA, offB, n, nfp2, half);
  int l = blockIdx.x;
  if (l >= half) return;
  int gi = threadIdx.x;        // 256 granules = 2 hl * 128 ks8
  int hl = gi >> 7;
  int k0 = (gi & 127) * 8;
  const float* hb = h + (size_t)b * CH * LMAX;
  unsigned short v[8];
#pragma unroll
  for (int t = 0; t < 8; t += 2) {
    int c = (k0 + t) >> 1;
    float2 p = *(const float2*)(hb + (size_t)c * LMAX + 2 * l);
    unsigned short hi, lo;
    hilo(p.x, hi, lo); v[t] = hl ? lo : hi;
    hilo(p.y, hi, lo); v[t + 1] = hl ? lo : hi;
  }
  uint4 o;
  o.x = (unsigned)v[0] | ((unsigned)v[1] << 16);
  o.y = (unsigned)v[2] | ((unsigned)v[3] << 16);
  o.z = (unsigned)v[4] | ((unsigned)v[5] << 16);
  o.w = (unsigned)v[6] | ((unsigned)v[7] << 16);
  *(uint4*)(ws + offC0 + ((size_t)l << 12) + (hl << 11) + k0 * 2) = o;
}

// ---------- suffix: cur[i] = h[.., i+half] for i in [half, nfp2) -> bufA pairs ----------
__global__ __launch_bounds__(256) void suffix_k(const float* __restrict__ h,
                                                const int* __restrict__ Nvec,
                                                char* __restrict__ ws) {
  int b = blockIdx.z;
  size_t offC0, offA, offB; int n, nfp2, half;
  layout(Nvec, b, offC0, offA, offB, n, nfp2, half);
  int lp = blockIdx.x;
  if (lp >= (nfp2 >> 1)) return;
  if (2 * lp + 1 < half) return;
  int gi = threadIdx.x;
  int hl = gi >> 7;
  int k0 = (gi & 127) * 8;
  const float* hb = h + (size_t)b * CH * LMAX;
  char* dst = ws + offA + ((size_t)lp << 12) + (hl << 11) + k0 * 2;
  if (2 * lp >= half) {
    unsigned short v[8];
#pragma unroll
    for (int t = 0; t < 8; ++t) {
      int k = k0 + t;
      int c = k >> 1, j = k & 1;
      float x = hb[(size_t)c * LMAX + 2 * lp + j + half];
      unsigned short hi, lo; hilo(x, hi, lo);
      v[t] = hl ? lo : hi;
    }
    uint4 o;
    o.x = (unsigned)v[0] | ((unsigned)v[1] << 16);
    o.y = (unsigned)v[2] | ((unsigned)v[3] << 16);
    o.z = (unsigned)v[4] | ((unsigned)v[5] << 16);
    o.w = (unsigned)v[6] | ((unsigned)v[7] << 16);
    *(uint4*)dst = o;
  } else {
    // boundary pair: only odd elements (i = 2lp+1) belong to suffix
#pragma unroll
    for (int t = 1; t < 8; t += 2) {
      int k = k0 + t;
      int c = k >> 1;
      float x = hb[(size_t)c * LMAX + 2 * lp + 1 + half];
      unsigned short hi, lo; hilo(x, hi, lo);
      *(unsigned short*)(ws + offA + ((size_t)lp << 12) + (hl << 11) + k * 2) = (hl ? lo : hi);
    }
  }
}

// ---------- one reduction level: split-bf16 MFMA GEMM + fused gate ----------
__global__ __launch_bounds__(256) void mfma_level_k(const float* __restrict__ bias,
                                                    const int* __restrict__ Nvec,
                                                    char* __restrict__ ws,
                                                    float* __restrict__ dout, int level) {
  __shared__ char smem[40960];  // As 192*128 = 24576, Bs 128*128 = 16384
  const int b = blockIdx.z;
  size_t offC0, offA, offB; int n, nfp2, half;
  layout(Nvec, b, offC0, offA, offB, n, nfp2, half);

  int cols;
  size_t inOff, outOff;
  if (level == 0) {
    if (half == 0) return;
    cols = half;
    inOff = offC0;
    outOff = offA;
  } else {
    int w = nfp2 >> (level - 1);
    if (w < 2) return;
    cols = w >> 1;
    inOff = (level & 1) ? offA : offB;
    outOff = (level & 1) ? offB : offA;
  }
  const bool fin = (level > 0) && ((nfp2 >> level) == 1);
  const int l0 = blockIdx.x * 128;
  if (l0 >= cols) return;
  const int o0 = blockIdx.y * 64;

  const int tid = threadIdx.x;
  const int lane = tid & 63, wid = tid >> 6;
  const int lane15 = lane & 15, lq = lane >> 4;
  char* As = smem;
  char* Bs = smem + 24576;
  const char* inp = ws + inOff;

  f4v acc[12][2];
#pragma unroll
  for (int m = 0; m < 12; ++m)
#pragma unroll
    for (int cf = 0; cf < 2; ++cf) acc[m][cf] = (f4v){0.f, 0.f, 0.f, 0.f};

#pragma unroll 1
  for (int kc = 0; kc < 32; ++kc) {
    // stage A tile: 192 rows x 128 B
#pragma unroll
    for (int q = 0; q < 6; ++q) {
      int d = q * 4096 + tid * 16;
      int r = d >> 7;
      int p = (d >> 4) & 7;
      int o = ((r >> 6) << 9) + o0 + (r & 63);
      int g = p ^ (r & 7);
      gload16(ws + (((size_t)(kc * 1536 + o)) << 7) + (g << 4),
              As + q * 4096 + wid * 1024);
    }
    // stage B tile: 128 rows x 128 B (gather with baked swizzle)
#pragma unroll
    for (int q = 0; q < 4; ++q) {
      int d = q * 4096 + tid * 16;
      int l = d >> 7;
      int p = (d >> 4) & 7;
      int lc = l0 + l; if (lc > cols - 1) lc = cols - 1;
      int g = p ^ (l & 7);
      gload16(inp + ((size_t)lc << 12) + ((size_t)(g >> 2) << 11) + (kc << 6) + ((g & 3) << 4),
              Bs + q * 4096 + wid * 1024);
    }
    __syncthreads();

    s8v bh[2], bl[2];
#pragma unroll
    for (int cf = 0; cf < 2; ++cf) {
      int l = wid * 32 + cf * 16 + lane15;
      int ph = (0 * 4 + lq) ^ (l & 7);
      int pl = (1 * 4 + lq) ^ (l & 7);
      bh[cf] = *(const s8v*)(Bs + l * 128 + ph * 16);
      bl[cf] = *(const s8v*)(Bs + l * 128 + pl * 16);
    }
#pragma unroll
    for (int m = 0; m < 12; ++m) {
      int r = m * 16 + lane15;
      s8v ah = *(const s8v*)(As + r * 128 + ((lq) ^ (r & 7)) * 16);
      s8v al = *(const s8v*)(As + r * 128 + ((4 + lq) ^ (r & 7)) * 16);
      acc[m][0] = __builtin_amdgcn_mfma_f32_16x16x32_bf16(ah, bh[0], acc[m][0], 0, 0, 0);
      acc[m][1] = __builtin_amdgcn_mfma_f32_16x16x32_bf16(ah, bh[1], acc[m][1], 0, 0, 0);
      acc[m][0] = __builtin_amdgcn_mfma_f32_16x16x32_bf16(ah, bl[0], acc[m][0], 0, 0, 0);
      acc[m][1] = __builtin_amdgcn_mfma_f32_16x16x32_bf16(ah, bl[1], acc[m][1], 0, 0, 0);
      acc[m][0] = __builtin_amdgcn_mfma_f32_16x16x32_bf16(al, bh[0], acc[m][0], 0, 0, 0);
      acc[m][1] = __builtin_amdgcn_mfma_f32_16x16x32_bf16(al, bh[1], acc[m][1], 0, 0, 0);
    }
    __syncthreads();
  }

  // epilogue: gate in registers, store bf16 hi/lo pair-major (or final fp32)
  char* outp = ws + outOff;
#pragma unroll
  for (int rr = 0; rr < 4; ++rr) {
#pragma unroll
    for (int cf = 0; cf < 2; ++cf) {
      f4v vl = acc[rr][cf], vr = acc[4 + rr][cf], vg = acc[8 + rr][cf];
#pragma unroll
      for (int j = 0; j < 4; ++j) {
        int c = o0 + rr * 16 + lq * 4 + j;
        int l = l0 + wid * 32 + cf * 16 + lane15;
        if (l >= cols) continue;
        float zl = vl[j] + bias[c];
        float zr = vr[j] + bias[CH + c];
        float zg = vg[j] + bias[2 * CH + c];
        float g = 1.f / (1.f + __expf(-zg));
        float rt = 1.f - 2.f / (1.f + __expf(2.f * zr));
        float val = zl * g + rt * (1.f - g);
        if (fin) {
          if (l == 0) dout[(size_t)b * CH + c] = val;
        } else {
          unsigned short hi, lo; hilo(val, hi, lo);
          char* orow = outp + ((size_t)(l >> 1) << 12) + ((size_t)(2 * c + (l & 1)) << 1);
          *(unsigned short*)(orow) = hi;
          *(unsigned short*)(orow + 2048) = lo;
        }
      }
    }
  }
}

extern "C" void kernel_launch(void* const* d_in, const int* in_sizes, int n_in,
                              void* d_out, int out_size, void* d_ws, size_t ws_size,
                              hipStream_t stream) {
  const float* h = (const float*)d_in[0];
  const float* W = (const float*)d_in[1];
  const float* bias = (const float*)d_in[2];
  const int* Nvec = (const int*)d_in[3];
  float* dout = (float*)d_out;
  char* ws = (char*)d_ws;

  prep_w_k<<<dim3(192), 256, 0, stream>>>(W, ws);
  conv0_k<<<dim3(2048, 1, BATCH), 256, 0, stream>>>(h, Nvec, ws);
  suffix_k<<<dim3(2048, 1, BATCH), 256, 0, stream>>>(h, Nvec, ws);
  mfma_level_k<<<dim3(16, 8, BATCH), 256, 0, stream>>>(bias, Nvec, ws, dout, 0);
  for (int lev = 1; lev <= 12; ++lev) {
    int tiles = (lev < 5) ? (32 >> lev) : 1;
    mfma_level_k<<<dim3(tiles, 8, BATCH), 256, 0, stream>>>(bias, Nvec, ws, dout, lev);
  }
}

// Round 3
// 1343.166 us; speedup vs baseline: 2.7289x; 1.2926x over previous
//
#include <hip/hip_runtime.h>

#define BATCH 16
#define CH 512
#define OC 1536
#define KDIM 1024
#define LMAX 4096
#define WGLOB_SZ 6291456  // 32 kc * 1536 rows * 128 B

typedef __attribute__((ext_vector_type(8))) short s8v;
typedef __attribute__((ext_vector_type(4))) float f4v;

__device__ __forceinline__ int nfp2_of(int n) { return 1 << (31 - __clz(n)); }

__device__ __forceinline__ unsigned short f2bf(float x) {
  union { float f; unsigned u; } v; v.f = x;
  unsigned r = v.u + 0x7fffu + ((v.u >> 16) & 1u);
  return (unsigned short)(r >> 16);
}
__device__ __forceinline__ float bf2f(unsigned short b) {
  union { unsigned u; float f; } v; v.u = ((unsigned)b) << 16; return v.f;
}
__device__ __forceinline__ void hilo(float x, unsigned short& hi, unsigned short& lo) {
  hi = f2bf(x);
  lo = f2bf(x - bf2f(hi));
}

// per-batch arena layout (device-computed from Nvec)
__device__ __forceinline__ void layout(const int* __restrict__ Nvec, int b,
                                       size_t& offC0, size_t& offA, size_t& offB,
                                       int& n, int& nfp2, int& half) {
  size_t c0t = 0, at = 0, bt = 0, c0o = 0, ao = 0, bo = 0;
  n = 2; nfp2 = 2; half = 0;
#pragma unroll 1
  for (int i = 0; i < BATCH; ++i) {
    int ni = Nvec[i];
    int f = nfp2_of(ni);
    int hf = ni - f;
    size_t cs = (size_t)((hf + 127) & ~127) << 12;
    size_t as = (size_t)(f >> 1) << 12;
    size_t bs = (size_t)(f >> 2) << 12;
    if (i < b) { c0o += cs; ao += as; bo += bs; }
    if (i == b) { n = ni; nfp2 = f; half = hf; }
    c0t += cs; at += as; bt += bs;
  }
  offC0 = (size_t)WGLOB_SZ + c0o;
  offA = (size_t)WGLOB_SZ + c0t + ao;
  offB = (size_t)WGLOB_SZ + c0t + at + bo;
}

__device__ __forceinline__ void gload16(const void* g, void* l) {
  __builtin_amdgcn_global_load_lds((const __attribute__((address_space(1))) void*)g,
                                   (__attribute__((address_space(3))) void*)l, 16, 0, 0);
}

// ---------- W prep: W[o][k] fp32 -> Wglob[kc][o][hi 32bf16 | lo 32bf16] ----------
__global__ __launch_bounds__(256) void prep_w_k(const float* __restrict__ W, char* __restrict__ ws) {
  int idx = blockIdx.x * 256 + threadIdx.x;  // idx = kc*1536 + o
  if (idx >= 32 * 1536) return;
  int kc = idx / 1536;
  int o = idx - kc * 1536;
  const float* src = W + (size_t)o * KDIM + kc * 32;
  unsigned short hb[32], lb[32];
#pragma unroll
  for (int t = 0; t < 32; ++t) hilo(src[t], hb[t], lb[t]);
  uint4* d4 = (uint4*)(ws + ((size_t)idx << 7));
#pragma unroll
  for (int q = 0; q < 4; ++q) {
    uint4 v;
    v.x = (unsigned)hb[q*8+0] | ((unsigned)hb[q*8+1] << 16);
    v.y = (unsigned)hb[q*8+2] | ((unsigned)hb[q*8+3] << 16);
    v.z = (unsigned)hb[q*8+4] | ((unsigned)hb[q*8+5] << 16);
    v.w = (unsigned)hb[q*8+6] | ((unsigned)hb[q*8+7] << 16);
    d4[q] = v;
  }
#pragma unroll
  for (int q = 0; q < 4; ++q) {
    uint4 v;
    v.x = (unsigned)lb[q*8+0] | ((unsigned)lb[q*8+1] << 16);
    v.y = (unsigned)lb[q*8+2] | ((unsigned)lb[q*8+3] << 16);
    v.z = (unsigned)lb[q*8+4] | ((unsigned)lb[q*8+5] << 16);
    v.w = (unsigned)lb[q*8+6] | ((unsigned)lb[q*8+7] << 16);
    d4[4 + q] = v;
  }
}

// ---------- h reorg (replaces conv0/suffix): coalesced read + LDS transpose ----------
// mode 0: dst pair-col d in [0, half), src cols (2d, 2d+1), dst = C0 buffer
// mode 1: dst pair-col d in [half>>1, nfp2>>1), src cols (2d+half, 2d+1+half), dst = bufA
// Each block: 32 dst cols x 64 channels. LDS tile [32 d][2 hl][128 k] 2B, XOR-swizzled.
__global__ __launch_bounds__(256) void reorg_h_k(const float* __restrict__ h,
                                                 const int* __restrict__ Nvec,
                                                 char* __restrict__ ws,
                                                 float* __restrict__ dout, int mode) {
  __shared__ char T[32 * 512];  // 16 KB
  const int b = blockIdx.z;
  size_t offC0, offA, offB; int n, nfp2, half;
  layout(Nvec, b, offC0, offA, offB, n, nfp2, half);
  const int tid = threadIdx.x;
  const int c0 = blockIdx.y * 64;

  if (mode == 1 && nfp2 == 1) {  // degenerate: answer is h[:, 0]
    if (blockIdx.x == 0 && tid < 64)
      dout[(size_t)b * CH + c0 + tid] = h[(size_t)b * CH * LMAX + (size_t)(c0 + tid) * LMAX];
    return;
  }

  const int d0 = blockIdx.x * 32;
  int dlo, dhi, soff;
  size_t base;
  if (mode == 0) { dlo = 0; dhi = half; soff = 0; base = offC0; }
  else { dlo = half >> 1; dhi = nfp2 >> 1; soff = half; base = offA; }
  if (d0 >= dhi || d0 + 32 <= dlo) return;

  const float* hb = h + (size_t)b * CH * LMAX;

  // phase 1: coalesced float2 read (lanes span dst cols) + convert + swizzled LDS write
#pragma unroll
  for (int q = 0; q < 8; ++q) {
    int id = q * 256 + tid;
    int cl = id >> 5;          // channel within tile 0..63
    int dl = id & 31;          // dst col within tile
    int d = d0 + dl;
    bool ok = (d < dhi) && (d >= dlo);
    float2 v;
    v.x = 0.f; v.y = 0.f;
    if (ok) v = *(const float2*)(hb + (size_t)(c0 + cl) * LMAX + 2 * d + soff);
    unsigned short h0, l0_, h1, l1_;
    hilo(v.x, h0, l0_);
    hilo(v.y, h1, l1_);
    int g = cl >> 2;
    int byte_hi = dl * 512 + ((g ^ (dl & 15)) << 4) + (cl & 3) * 4;
    *(unsigned*)(T + byte_hi) = (unsigned)h0 | ((unsigned)h1 << 16);
    *(unsigned*)(T + byte_hi + 256) = (unsigned)l0_ | ((unsigned)l1_ << 16);
  }
  __syncthreads();
  // phase 2: contiguous 16B stores to pair-major records
#pragma unroll
  for (int qq = 0; qq < 4; ++qq) {
    int gid = qq * 256 + tid;
    int dl = gid >> 5;
    int hl = (gid >> 4) & 1;
    int seg = gid & 15;
    int d = d0 + dl;
    if (d >= dhi || d < dlo) continue;
    uint4 val = *(const uint4*)(T + dl * 512 + hl * 256 + ((seg ^ (dl & 15)) << 4));
    *(uint4*)(ws + base + ((size_t)d << 12) + (hl << 11) + (size_t)c0 * 4 + seg * 16) = val;
  }
}

// ---------- one reduction level: split-bf16 MFMA GEMM + fused gate, 2-phase pipeline ----------
__global__ __launch_bounds__(256) void mfma_level_k(const float* __restrict__ bias,
                                                    const int* __restrict__ Nvec,
                                                    char* __restrict__ ws,
                                                    float* __restrict__ dout, int level) {
  __shared__ char smem[81920];  // 2 x (As 24576 + Bs 16384)
  const int b = blockIdx.z;
  size_t offC0, offA, offB; int n, nfp2, half;
  layout(Nvec, b, offC0, offA, offB, n, nfp2, half);

  int cols;
  size_t inOff, outOff;
  if (level == 0) {
    if (half == 0) return;
    cols = half;
    inOff = offC0;
    outOff = offA;
  } else {
    int w = nfp2 >> (level - 1);
    if (w < 2) return;
    cols = w >> 1;
    inOff = (level & 1) ? offA : offB;
    outOff = (level & 1) ? offB : offA;
  }
  const bool fin = (level > 0) && ((nfp2 >> level) == 1);
  const int l0 = blockIdx.x * 128;
  if (l0 >= cols) return;
  const int o0 = blockIdx.y * 64;

  const int tid = threadIdx.x;
  const int lane = tid & 63, wid = tid >> 6;
  const int lane15 = lane & 15, lq = lane >> 4;
  const char* inp = ws + inOff;

  // staging offsets (kc-independent parts)
  unsigned aoff[6]; int adst[6];
#pragma unroll
  for (int q = 0; q < 6; ++q) {
    int d = q * 4096 + tid * 16;
    int r = d >> 7;
    int p = (d >> 4) & 7;
    int o = ((r >> 6) << 9) + o0 + (r & 63);
    int g = p ^ (r & 7);
    aoff[q] = ((unsigned)o << 7) + (g << 4);
    adst[q] = q * 4096 + wid * 1024;
  }
  unsigned boff[4]; int bdst[4];
#pragma unroll
  for (int q = 0; q < 4; ++q) {
    int d = q * 4096 + tid * 16;
    int l = d >> 7;
    int p = (d >> 4) & 7;
    int lc = l0 + l; if (lc > cols - 1) lc = cols - 1;
    int g = p ^ (l & 7);
    boff[q] = ((unsigned)lc << 12) + ((unsigned)(g >> 2) << 11) + ((g & 3) << 4);
    bdst[q] = q * 4096 + wid * 1024;
  }

#define STAGE(kc, sel) do {                                                  \
    char* Ab = smem + (sel) * 40960;                                         \
    char* Bb = Ab + 24576;                                                   \
    unsigned ka = (unsigned)(kc) * (1536u << 7);                             \
    unsigned kb = (unsigned)(kc) << 6;                                       \
    _Pragma("unroll") for (int q = 0; q < 6; ++q)                            \
      gload16(ws + ka + aoff[q], Ab + adst[q]);                              \
    _Pragma("unroll") for (int q = 0; q < 4; ++q)                            \
      gload16(inp + kb + boff[q], Bb + bdst[q]);                             \
  } while (0)

  f4v acc[12][2];
#pragma unroll
  for (int m = 0; m < 12; ++m)
#pragma unroll
    for (int cf = 0; cf < 2; ++cf) acc[m][cf] = (f4v){0.f, 0.f, 0.f, 0.f};

  STAGE(0, 0);
  __syncthreads();

#pragma unroll 1
  for (int kc = 0; kc < 32; ++kc) {
    const int cur = kc & 1;
    if (kc + 1 < 32) STAGE(kc + 1, cur ^ 1);  // prefetch overlaps this kc's compute
    const char* Asb = smem + cur * 40960;
    const char* Bsb = Asb + 24576;

    s8v bh[2], bl[2];
#pragma unroll
    for (int cf = 0; cf < 2; ++cf) {
      int l = wid * 32 + cf * 16 + lane15;
      int ph = (0 * 4 + lq) ^ (l & 7);
      int pl = (1 * 4 + lq) ^ (l & 7);
      bh[cf] = *(const s8v*)(Bsb + l * 128 + ph * 16);
      bl[cf] = *(const s8v*)(Bsb + l * 128 + pl * 16);
    }
#pragma unroll
    for (int m = 0; m < 12; ++m) {
      int r = m * 16 + lane15;
      s8v ah = *(const s8v*)(Asb + r * 128 + ((lq) ^ (r & 7)) * 16);
      s8v al = *(const s8v*)(Asb + r * 128 + ((4 + lq) ^ (r & 7)) * 16);
      acc[m][0] = __builtin_amdgcn_mfma_f32_16x16x32_bf16(ah, bh[0], acc[m][0], 0, 0, 0);
      acc[m][1] = __builtin_amdgcn_mfma_f32_16x16x32_bf16(ah, bh[1], acc[m][1], 0, 0, 0);
      acc[m][0] = __builtin_amdgcn_mfma_f32_16x16x32_bf16(ah, bl[0], acc[m][0], 0, 0, 0);
      acc[m][1] = __builtin_amdgcn_mfma_f32_16x16x32_bf16(ah, bl[1], acc[m][1], 0, 0, 0);
      acc[m][0] = __builtin_amdgcn_mfma_f32_16x16x32_bf16(al, bh[0], acc[m][0], 0, 0, 0);
      acc[m][1] = __builtin_amdgcn_mfma_f32_16x16x32_bf16(al, bh[1], acc[m][1], 0, 0, 0);
    }
    __syncthreads();
  }
#undef STAGE

  // epilogue: gate in registers, store bf16 hi/lo pair-major (or final fp32)
  char* outp = ws + outOff;
#pragma unroll
  for (int rr = 0; rr < 4; ++rr) {
#pragma unroll
    for (int cf = 0; cf < 2; ++cf) {
      f4v vl = acc[rr][cf], vr = acc[4 + rr][cf], vg = acc[8 + rr][cf];
#pragma unroll
      for (int j = 0; j < 4; ++j) {
        int c = o0 + rr * 16 + lq * 4 + j;
        int l = l0 + wid * 32 + cf * 16 + lane15;
        if (l >= cols) continue;
        float zl = vl[j] + bias[c];
        float zr = vr[j] + bias[CH + c];
        float zg = vg[j] + bias[2 * CH + c];
        float g = 1.f / (1.f + __expf(-zg));
        float rt = 1.f - 2.f / (1.f + __expf(2.f * zr));
        float val = zl * g + rt * (1.f - g);
        if (fin) {
          if (l == 0) dout[(size_t)b * CH + c] = val;
        } else {
          unsigned short hi, lo; hilo(val, hi, lo);
          char* orow = outp + ((size_t)(l >> 1) << 12) + ((size_t)(2 * c + (l & 1)) << 1);
          *(unsigned short*)(orow) = hi;
          *(unsigned short*)(orow + 2048) = lo;
        }
      }
    }
  }
}

extern "C" void kernel_launch(void* const* d_in, const int* in_sizes, int n_in,
                              void* d_out, int out_size, void* d_ws, size_t ws_size,
                              hipStream_t stream) {
  const float* h = (const float*)d_in[0];
  const float* W = (const float*)d_in[1];
  const float* bias = (const float*)d_in[2];
  const int* Nvec = (const int*)d_in[3];
  float* dout = (float*)d_out;
  char* ws = (char*)d_ws;

  prep_w_k<<<dim3(192), 256, 0, stream>>>(W, ws);
  reorg_h_k<<<dim3(64, 8, BATCH), 256, 0, stream>>>(h, Nvec, ws, dout, 0);
  reorg_h_k<<<dim3(64, 8, BATCH), 256, 0, stream>>>(h, Nvec, ws, dout, 1);
  mfma_level_k<<<dim3(16, 8, BATCH), 256, 0, stream>>>(bias, Nvec, ws, dout, 0);
  for (int lev = 1; lev <= 12; ++lev) {
    int tiles = (lev < 5) ? (32 >> lev) : 1;
    mfma_level_k<<<dim3(tiles, 8, BATCH), 256, 0, stream>>>(bias, Nvec, ws, dout, lev);
  }
}

// Round 4
// 1006.718 us; speedup vs baseline: 3.6409x; 1.3342x over previous
//
#include <hip/hip_runtime.h>

#define BATCH 16
#define CH 512
#define OC 1536
#define KDIM 1024
#define LMAX 4096
#define WGLOB_SZ 6291456  // 32 kc * 1536 rows * 128 B

typedef __attribute__((ext_vector_type(8))) short s8v;
typedef __attribute__((ext_vector_type(4))) float f4v;

__device__ __forceinline__ int nfp2_of(int n) { return 1 << (31 - __clz(n)); }

__device__ __forceinline__ unsigned short f2bf(float x) {
  union { float f; unsigned u; } v; v.f = x;
  unsigned r = v.u + 0x7fffu + ((v.u >> 16) & 1u);
  return (unsigned short)(r >> 16);
}
__device__ __forceinline__ float bf2f(unsigned short b) {
  union { unsigned u; float f; } v; v.u = ((unsigned)b) << 16; return v.f;
}
__device__ __forceinline__ void hilo(float x, unsigned short& hi, unsigned short& lo) {
  hi = f2bf(x);
  lo = f2bf(x - bf2f(hi));
}

// per-batch arena layout (device-computed from Nvec)
__device__ __forceinline__ void layout(const int* __restrict__ Nvec, int b,
                                       size_t& offC0, size_t& offA, size_t& offB,
                                       int& n, int& nfp2, int& half) {
  size_t c0t = 0, at = 0, bt = 0, c0o = 0, ao = 0, bo = 0;
  n = 2; nfp2 = 2; half = 0;
#pragma unroll 1
  for (int i = 0; i < BATCH; ++i) {
    int ni = Nvec[i];
    int f = nfp2_of(ni);
    int hf = ni - f;
    size_t cs = (size_t)((hf + 127) & ~127) << 12;
    size_t as = (size_t)(f >> 1) << 12;
    size_t bs = (size_t)(f >> 2) << 12;
    if (i < b) { c0o += cs; ao += as; bo += bs; }
    if (i == b) { n = ni; nfp2 = f; half = hf; }
    c0t += cs; at += as; bt += bs;
  }
  offC0 = (size_t)WGLOB_SZ + c0o;
  offA = (size_t)WGLOB_SZ + c0t + ao;
  offB = (size_t)WGLOB_SZ + c0t + at + bo;
}

__device__ __forceinline__ void gload16(const void* g, void* l) {
  __builtin_amdgcn_global_load_lds((const __attribute__((address_space(1))) void*)g,
                                   (__attribute__((address_space(3))) void*)l, 16, 0, 0);
}

// ---------- W prep: W[o][k] fp32 -> Wglob[kc][o][hi 32bf16 | lo 32bf16] ----------
__global__ __launch_bounds__(256) void prep_w_k(const float* __restrict__ W, char* __restrict__ ws) {
  int idx = blockIdx.x * 256 + threadIdx.x;  // idx = kc*1536 + o
  if (idx >= 32 * 1536) return;
  int kc = idx / 1536;
  int o = idx - kc * 1536;
  const float* src = W + (size_t)o * KDIM + kc * 32;
  unsigned short hb[32], lb[32];
#pragma unroll
  for (int t = 0; t < 32; ++t) hilo(src[t], hb[t], lb[t]);
  uint4* d4 = (uint4*)(ws + ((size_t)idx << 7));
#pragma unroll
  for (int q = 0; q < 4; ++q) {
    uint4 v;
    v.x = (unsigned)hb[q*8+0] | ((unsigned)hb[q*8+1] << 16);
    v.y = (unsigned)hb[q*8+2] | ((unsigned)hb[q*8+3] << 16);
    v.z = (unsigned)hb[q*8+4] | ((unsigned)hb[q*8+5] << 16);
    v.w = (unsigned)hb[q*8+6] | ((unsigned)hb[q*8+7] << 16);
    d4[q] = v;
  }
#pragma unroll
  for (int q = 0; q < 4; ++q) {
    uint4 v;
    v.x = (unsigned)lb[q*8+0] | ((unsigned)lb[q*8+1] << 16);
    v.y = (unsigned)lb[q*8+2] | ((unsigned)lb[q*8+3] << 16);
    v.z = (unsigned)lb[q*8+4] | ((unsigned)lb[q*8+5] << 16);
    v.w = (unsigned)lb[q*8+6] | ((unsigned)lb[q*8+7] << 16);
    d4[4 + q] = v;
  }
}

// ---------- h reorg: coalesced read + LDS transpose ----------
__global__ __launch_bounds__(256) void reorg_h_k(const float* __restrict__ h,
                                                 const int* __restrict__ Nvec,
                                                 char* __restrict__ ws,
                                                 float* __restrict__ dout, int mode) {
  __shared__ char T[32 * 512];  // 16 KB
  const int b = blockIdx.z;
  size_t offC0, offA, offB; int n, nfp2, half;
  layout(Nvec, b, offC0, offA, offB, n, nfp2, half);
  const int tid = threadIdx.x;
  const int c0 = blockIdx.y * 64;

  if (mode == 1 && nfp2 == 1) {  // degenerate: answer is h[:, 0]
    if (blockIdx.x == 0 && tid < 64)
      dout[(size_t)b * CH + c0 + tid] = h[(size_t)b * CH * LMAX + (size_t)(c0 + tid) * LMAX];
    return;
  }

  const int d0 = blockIdx.x * 32;
  int dlo, dhi, soff;
  size_t base;
  if (mode == 0) { dlo = 0; dhi = half; soff = 0; base = offC0; }
  else { dlo = half >> 1; dhi = nfp2 >> 1; soff = half; base = offA; }
  if (d0 >= dhi || d0 + 32 <= dlo) return;

  const float* hb = h + (size_t)b * CH * LMAX;

#pragma unroll
  for (int q = 0; q < 8; ++q) {
    int id = q * 256 + tid;
    int cl = id >> 5;
    int dl = id & 31;
    int d = d0 + dl;
    bool ok = (d < dhi) && (d >= dlo);
    float2 v;
    v.x = 0.f; v.y = 0.f;
    if (ok) v = *(const float2*)(hb + (size_t)(c0 + cl) * LMAX + 2 * d + soff);
    unsigned short h0, l0_, h1, l1_;
    hilo(v.x, h0, l0_);
    hilo(v.y, h1, l1_);
    int g = cl >> 2;
    int byte_hi = dl * 512 + ((g ^ (dl & 15)) << 4) + (cl & 3) * 4;
    *(unsigned*)(T + byte_hi) = (unsigned)h0 | ((unsigned)h1 << 16);
    *(unsigned*)(T + byte_hi + 256) = (unsigned)l0_ | ((unsigned)l1_ << 16);
  }
  __syncthreads();
#pragma unroll
  for (int qq = 0; qq < 4; ++qq) {
    int gid = qq * 256 + tid;
    int dl = gid >> 5;
    int hl = (gid >> 4) & 1;
    int seg = gid & 15;
    int d = d0 + dl;
    if (d >= dhi || d < dlo) continue;
    uint4 val = *(const uint4*)(T + dl * 512 + hl * 256 + ((seg ^ (dl & 15)) << 4));
    *(uint4*)(ws + base + ((size_t)d << 12) + (hl << 11) + (size_t)c0 * 4 + seg * 16) = val;
  }
}

// ---------- one reduction level: split-bf16 MFMA GEMM + fused gate ----------
// 192x256 tile, 512 threads, 8 waves = 2 row-groups (3 parts x 32 ch) x 4 col-groups.
// 1D grid: id = (z*tiles + x)*8 + y  -> y (channel group) pinned to XCD via id%8.
__global__ __launch_bounds__(512, 2) void mfma_level_k(const float* __restrict__ bias,
                                                       const int* __restrict__ Nvec,
                                                       char* __restrict__ ws,
                                                       float* __restrict__ dout,
                                                       int level, int tiles) {
  __shared__ char smem[114688];  // 2 x (As 24576 + Bs 32768)
  const int id = blockIdx.x;
  const int o0 = (id & 7) * 64;
  const int r2 = id >> 3;
  const int xb = r2 % tiles;
  const int b = r2 / tiles;

  size_t offC0, offA, offB; int n, nfp2, half;
  layout(Nvec, b, offC0, offA, offB, n, nfp2, half);

  int cols;
  size_t inOff, outOff;
  if (level == 0) {
    if (half == 0) return;
    cols = half;
    inOff = offC0;
    outOff = offA;
  } else {
    int w = nfp2 >> (level - 1);
    if (w < 2) return;
    cols = w >> 1;
    inOff = (level & 1) ? offA : offB;
    outOff = (level & 1) ? offB : offA;
  }
  const bool fin = (level > 0) && ((nfp2 >> level) == 1);
  const int l0 = xb * 256;
  if (l0 >= cols) return;

  const int tid = threadIdx.x;
  const int lane = tid & 63, wid = tid >> 6;
  const int lane15 = lane & 15, lq = lane >> 4;
  const int rg = wid & 1, cg = wid >> 1;
  const char* inp = ws + inOff;

  // staging offsets (kc-independent parts)
  unsigned aoff[3]; int adst[3];
#pragma unroll
  for (int q = 0; q < 3; ++q) {
    int d = q * 8192 + tid * 16;
    int r = d >> 7;
    int p = (d >> 4) & 7;
    int o = ((r >> 6) << 9) + o0 + (r & 63);
    int g = p ^ (r & 7);
    aoff[q] = ((unsigned)o << 7) + (g << 4);
    adst[q] = q * 8192 + wid * 1024;
  }
  unsigned boff[4]; int bdst[4];
#pragma unroll
  for (int q = 0; q < 4; ++q) {
    int d = q * 8192 + tid * 16;
    int l = d >> 7;
    int p = (d >> 4) & 7;
    int lc = l0 + l; if (lc > cols - 1) lc = cols - 1;
    int g = p ^ (l & 7);
    boff[q] = ((unsigned)lc << 12) + ((unsigned)(g >> 2) << 11) + ((g & 3) << 4);
    bdst[q] = q * 8192 + wid * 1024;
  }

#define STAGE(kc, sel) do {                                                  \
    char* Ab = smem + (sel) * 57344;                                         \
    char* Bb = Ab + 24576;                                                   \
    unsigned ka = (unsigned)(kc) * (1536u << 7);                             \
    unsigned kb = (unsigned)(kc) << 6;                                       \
    _Pragma("unroll") for (int q = 0; q < 3; ++q)                            \
      gload16(ws + ka + aoff[q], Ab + adst[q]);                              \
    _Pragma("unroll") for (int q = 0; q < 4; ++q)                            \
      gload16(inp + kb + boff[q], Bb + bdst[q]);                             \
  } while (0)

  f4v acc[6][4];
#pragma unroll
  for (int m = 0; m < 6; ++m)
#pragma unroll
    for (int cf = 0; cf < 4; ++cf) acc[m][cf] = (f4v){0.f, 0.f, 0.f, 0.f};

  STAGE(0, 0);
  __syncthreads();

#pragma unroll 1
  for (int kc = 0; kc < 32; ++kc) {
    const int cur = kc & 1;
    if (kc + 1 < 32) STAGE(kc + 1, cur ^ 1);  // prefetch overlaps this kc's compute
    const char* Asb = smem + cur * 57344;
    const char* Bsb = Asb + 24576;

    s8v bh[4], bl[4];
#pragma unroll
    for (int cf = 0; cf < 4; ++cf) {
      int ll = cg * 64 + cf * 16 + lane15;
      int ph = lq ^ (ll & 7);
      int pl = (4 + lq) ^ (ll & 7);
      bh[cf] = *(const s8v*)(Bsb + ll * 128 + ph * 16);
      bl[cf] = *(const s8v*)(Bsb + ll * 128 + pl * 16);
    }
#pragma unroll
    for (int m = 0; m < 6; ++m) {
      int rr = (m >> 1) * 64 + rg * 32 + (m & 1) * 16 + lane15;
      s8v ah = *(const s8v*)(Asb + rr * 128 + ((lq ^ (rr & 7)) << 4));
      s8v al = *(const s8v*)(Asb + rr * 128 + (((4 + lq) ^ (rr & 7)) << 4));
#pragma unroll
      for (int cf = 0; cf < 4; ++cf) {
        acc[m][cf] = __builtin_amdgcn_mfma_f32_16x16x32_bf16(ah, bh[cf], acc[m][cf], 0, 0, 0);
        acc[m][cf] = __builtin_amdgcn_mfma_f32_16x16x32_bf16(ah, bl[cf], acc[m][cf], 0, 0, 0);
        acc[m][cf] = __builtin_amdgcn_mfma_f32_16x16x32_bf16(al, bh[cf], acc[m][cf], 0, 0, 0);
      }
    }
    __syncthreads();
  }
#undef STAGE

  // epilogue: gate in registers, store bf16 hi/lo pair-major (or final fp32)
  char* outp = ws + outOff;
#pragma unroll
  for (int s = 0; s < 2; ++s) {
#pragma unroll
    for (int cf = 0; cf < 4; ++cf) {
      f4v vl = acc[s][cf], vr = acc[2 + s][cf], vg = acc[4 + s][cf];
      int l = l0 + cg * 64 + cf * 16 + lane15;
      if (l >= cols) continue;
#pragma unroll
      for (int j = 0; j < 4; ++j) {
        int c = o0 + rg * 32 + s * 16 + lq * 4 + j;
        float zl = vl[j] + bias[c];
        float zr = vr[j] + bias[CH + c];
        float zg = vg[j] + bias[2 * CH + c];
        float g = 1.f / (1.f + __expf(-zg));
        float rt = 1.f - 2.f / (1.f + __expf(2.f * zr));
        float val = zl * g + rt * (1.f - g);
        if (fin) {
          if (l == 0) dout[(size_t)b * CH + c] = val;
        } else {
          unsigned short hi, lo; hilo(val, hi, lo);
          char* orow = outp + ((size_t)(l >> 1) << 12) + ((size_t)(2 * c + (l & 1)) << 1);
          *(unsigned short*)(orow) = hi;
          *(unsigned short*)(orow + 2048) = lo;
        }
      }
    }
  }
}

extern "C" void kernel_launch(void* const* d_in, const int* in_sizes, int n_in,
                              void* d_out, int out_size, void* d_ws, size_t ws_size,
                              hipStream_t stream) {
  const float* h = (const float*)d_in[0];
  const float* W = (const float*)d_in[1];
  const float* bias = (const float*)d_in[2];
  const int* Nvec = (const int*)d_in[3];
  float* dout = (float*)d_out;
  char* ws = (char*)d_ws;

  prep_w_k<<<dim3(192), 256, 0, stream>>>(W, ws);
  reorg_h_k<<<dim3(64, 8, BATCH), 256, 0, stream>>>(h, Nvec, ws, dout, 0);
  reorg_h_k<<<dim3(64, 8, BATCH), 256, 0, stream>>>(h, Nvec, ws, dout, 1);

  // level 0: max half = 952 -> 4 tiles of 256
  mfma_level_k<<<dim3(4 * 8 * BATCH), 512, 0, stream>>>(bias, Nvec, ws, dout, 0, 4);
  for (int lev = 1; lev <= 12; ++lev) {
    int colsmax = LMAX >> lev;               // worst-case cols at this level
    int tiles = (colsmax + 255) / 256; if (tiles < 1) tiles = 1;
    mfma_level_k<<<dim3(tiles * 8 * BATCH), 512, 0, stream>>>(bias, Nvec, ws, dout, lev, tiles);
  }
}